// Round 1
// baseline (205.286 us; speedup 1.0000x reference)
//
#include <hip/hip_runtime.h>

// NT-Xent loss: z_i, z_j [4096,1024] f32 -> scalar f32 loss.
// loss = mean_i( log(sum_{j != i} exp(2*cos_sim(i,j))) - 2*cos_sim(i, i^1) )

#define N_ROWS 8192
#define HALF_N 4096
#define DIMK   1024
#define BM     128
#define BK     64
#define NPANEL (N_ROWS / BM)   // 64
#define NSLOTS (NPANEL * 2)    // 128 partial slots per row

typedef float        f32x4  __attribute__((ext_vector_type(4)));
typedef unsigned int u32x4  __attribute__((ext_vector_type(4)));
typedef __bf16       bf16x8 __attribute__((ext_vector_type(8)));

__device__ __forceinline__ unsigned short f32_to_bf16_rne(float f) {
    union { float f; unsigned int u; } v; v.f = f;
    unsigned int r = v.u + 0x7fffu + ((v.u >> 16) & 1u);
    return (unsigned short)(r >> 16);
}

// ---------------- Kernel 1: row L2-normalize, f32 -> bf16 --------------------
__global__ __launch_bounds__(256) void norm_rows_kernel(
    const float* __restrict__ z_i, const float* __restrict__ z_j,
    unsigned short* __restrict__ xn)
{
    const int row = blockIdx.x;
    const float* src = (row < HALF_N) ? (z_i + (size_t)row * DIMK)
                                      : (z_j + (size_t)(row - HALF_N) * DIMK);
    const int t = threadIdx.x;
    const float4 v = ((const float4*)src)[t];   // 256 threads * 4 = 1024 elems
    float ss = v.x * v.x + v.y * v.y + v.z * v.z + v.w * v.w;
    #pragma unroll
    for (int m = 1; m < 64; m <<= 1) ss += __shfl_xor(ss, m, 64);
    __shared__ float red[4];
    const int lane = t & 63, wave = t >> 6;
    if (lane == 0) red[wave] = ss;
    __syncthreads();
    ss = red[0] + red[1] + red[2] + red[3];
    const float rn = 1.0f / fmaxf(sqrtf(ss), 1e-8f);

    union { unsigned short s[4]; uint2 u; } pack;
    pack.s[0] = f32_to_bf16_rne(v.x * rn);
    pack.s[1] = f32_to_bf16_rne(v.y * rn);
    pack.s[2] = f32_to_bf16_rne(v.z * rn);
    pack.s[3] = f32_to_bf16_rne(v.w * rn);
    ((uint2*)(xn + (size_t)row * DIMK))[t] = pack.u;
}

// ---- Kernel 2: fused sim-GEMM (bf16 MFMA) + exp + per-row partial sums ------
// Block (ip,jp): 128x128 tile of sim = xn * xn^T. 256 thr = 4 waves (2x2),
// each wave owns a 64x64 sub-tile = 4x4 fragments of 16x16x32 MFMA.
// LDS tiles [128 rows][8 chunks of 8 bf16], XOR-swizzled: slot = r*8 + (c8 ^ (r&7)).
__global__ __launch_bounds__(256) void simexp_kernel(
    const unsigned short* __restrict__ xn,
    float* __restrict__ partial,   // [NSLOTS][N_ROWS]
    float* __restrict__ tgt)       // [N_ROWS] target logit per row
{
    __shared__ u32x4 As[BM * (BK / 8)];   // 16 KiB
    __shared__ u32x4 Bs[BM * (BK / 8)];   // 16 KiB

    const int jp = blockIdx.x, ip = blockIdx.y;
    const int t = threadIdx.x;
    const int lane = t & 63, wave = t >> 6;
    const int wm = wave >> 1, wn = wave & 1;
    const int rowBase = ip * BM, colBase = jp * BM;

    f32x4 acc[4][4];
    #pragma unroll
    for (int i = 0; i < 4; ++i)
        #pragma unroll
        for (int j = 0; j < 4; ++j) {
            f32x4 z = {0.0f, 0.0f, 0.0f, 0.0f};
            acc[i][j] = z;
        }

    for (int kt = 0; kt < DIMK; kt += BK) {
        // ---- stage: 256 thr x 4 chunks x 16B each for A and B ----
        u32x4 ra[4], rb[4];
        #pragma unroll
        for (int p = 0; p < 4; ++p) {
            const int id = p * 256 + t;          // 0..1023
            const int r  = id >> 3;              // tile row 0..127
            const int c8 = id & 7;               // 16B chunk in row
            ra[p] = ((const u32x4*)(xn + (size_t)(rowBase + r) * DIMK + kt))[c8];
            rb[p] = ((const u32x4*)(xn + (size_t)(colBase + r) * DIMK + kt))[c8];
        }
        __syncthreads();   // previous compute done before overwrite
        #pragma unroll
        for (int p = 0; p < 4; ++p) {
            const int id = p * 256 + t;
            const int r  = id >> 3;
            const int c8 = id & 7;
            const int slot = r * 8 + (c8 ^ (r & 7));
            As[slot] = ra[p];
            Bs[slot] = rb[p];
        }
        __syncthreads();

        // ---- compute: 2 x (8 ds_read_b128 + 16 MFMA) per wave ----
        #pragma unroll
        for (int kk = 0; kk < 2; ++kk) {
            const int kc = kk * 4 + (lane >> 4);   // k-chunk 0..7
            bf16x8 af[4], bfr[4];
            #pragma unroll
            for (int mi = 0; mi < 4; ++mi) {
                const int r = wm * 64 + mi * 16 + (lane & 15);
                af[mi] = __builtin_bit_cast(bf16x8, As[r * 8 + (kc ^ (r & 7))]);
            }
            #pragma unroll
            for (int ni = 0; ni < 4; ++ni) {
                const int r = wn * 64 + ni * 16 + (lane & 15);
                bfr[ni] = __builtin_bit_cast(bf16x8, Bs[r * 8 + (kc ^ (r & 7))]);
            }
            #pragma unroll
            for (int mi = 0; mi < 4; ++mi)
                #pragma unroll
                for (int ni = 0; ni < 4; ++ni)
                    acc[mi][ni] = __builtin_amdgcn_mfma_f32_16x16x32_bf16(
                        af[mi], bfr[ni], acc[mi][ni], 0, 0, 0);
        }
        __syncthreads();
    }

    // ---- epilogue: logits, diag mask, target capture, per-row exp sums ----
    // C/D layout (verified m89/m91): col = lane&15, row = (lane>>4)*4 + e
    const int colW = colBase + wn * 64;
    #pragma unroll
    for (int mi = 0; mi < 4; ++mi) {
        const int rbase = rowBase + wm * 64 + mi * 16 + ((lane >> 4) << 2);
        float rs[4] = {0.0f, 0.0f, 0.0f, 0.0f};
        #pragma unroll
        for (int ni = 0; ni < 4; ++ni) {
            const int gcol = colW + ni * 16 + (lane & 15);
            #pragma unroll
            for (int e = 0; e < 4; ++e) {
                const int grow = rbase + e;
                const float tv = acc[mi][ni][e] * 2.0f;     // /TEMPERATURE
                if (gcol == (grow ^ 1)) tgt[grow] = tv;     // exactly one writer
                rs[e] += (gcol == grow) ? 0.0f : __expf(tv);
            }
        }
        // reduce across the 16 lanes that share a row (lane&15 = col)
        #pragma unroll
        for (int m = 1; m < 16; m <<= 1) {
            #pragma unroll
            for (int e = 0; e < 4; ++e) rs[e] += __shfl_xor(rs[e], m, 64);
        }
        if ((lane & 15) == 0) {
            float* dst = partial + (size_t)(jp * 2 + wn) * N_ROWS + rbase;
            dst[0] = rs[0]; dst[1] = rs[1]; dst[2] = rs[2]; dst[3] = rs[3];
        }
    }
}

// ------------- Kernel 3: per-row LSE - target logit --------------------------
__global__ __launch_bounds__(256) void row_term_kernel(
    const float* __restrict__ partial, const float* __restrict__ tgt,
    float* __restrict__ terms)
{
    const int row = blockIdx.x * 256 + threadIdx.x;
    float s = 0.0f;
    for (int p = 0; p < NSLOTS; ++p) s += partial[(size_t)p * N_ROWS + row];
    terms[row] = logf(s) - tgt[row];
}

// ------------- Kernel 4: mean over rows --------------------------------------
__global__ __launch_bounds__(256) void loss_kernel(
    const float* __restrict__ terms, float* __restrict__ out)
{
    const int t = threadIdx.x;
    float s = 0.0f;
    for (int i = t; i < N_ROWS; i += 256) s += terms[i];
    #pragma unroll
    for (int m = 1; m < 64; m <<= 1) s += __shfl_xor(s, m, 64);
    __shared__ float red[4];
    if ((t & 63) == 0) red[t >> 6] = s;
    __syncthreads();
    if (t == 0) out[0] = (red[0] + red[1] + red[2] + red[3]) * (1.0f / N_ROWS);
}

extern "C" void kernel_launch(void* const* d_in, const int* in_sizes, int n_in,
                              void* d_out, int out_size, void* d_ws, size_t ws_size,
                              hipStream_t stream)
{
    const float* z_i = (const float*)d_in[0];
    const float* z_j = (const float*)d_in[1];
    float* out = (float*)d_out;

    // workspace layout
    unsigned short* xn = (unsigned short*)d_ws;                       // 16 MiB bf16
    float* partial = (float*)((char*)d_ws + (size_t)N_ROWS * DIMK * 2); // 4 MiB
    float* tgt     = partial + (size_t)NSLOTS * N_ROWS;               // 32 KiB
    float* terms   = tgt + N_ROWS;                                    // 32 KiB

    norm_rows_kernel<<<N_ROWS, 256, 0, stream>>>(z_i, z_j, xn);
    simexp_kernel<<<dim3(NPANEL, NPANEL), 256, 0, stream>>>(xn, partial, tgt);
    row_term_kernel<<<N_ROWS / 256, 256, 0, stream>>>(partial, tgt, terms);
    loss_kernel<<<1, 256, 0, stream>>>(terms, out);
}

// Round 2
// 159.291 us; speedup vs baseline: 1.2887x; 1.2887x over previous
//
#include <hip/hip_runtime.h>

// NT-Xent loss: z_i, z_j [4096,1024] f32 -> scalar f32 loss.
// loss = mean_i( log(sum_{j != i} exp(2*cos_sim(i,j))) - 2*cos_sim(i, i^1) )
//
// R2: symmetric-triangle GEMM (ip<=jp only, row+col exp-sum harvest) +
//     global_load_lds width=16 staging with inverse-swizzled source +
//     2-phase double-buffered LDS (one barrier per K-step).

#define N_ROWS 8192
#define HALF_N 4096
#define DIMK   1024
#define BM     128
#define BK     64
#define NPANEL (N_ROWS / BM)   // 64
#define NSLOTS (NPANEL * 2)    // 128 partial slots per row
#define KSTEPS (DIMK / BK)     // 16

typedef float        f32x4  __attribute__((ext_vector_type(4)));
typedef unsigned int u32x4  __attribute__((ext_vector_type(4)));
typedef __bf16       bf16x8 __attribute__((ext_vector_type(8)));

__device__ __forceinline__ unsigned short f32_to_bf16_rne(float f) {
    union { float f; unsigned int u; } v; v.f = f;
    unsigned int r = v.u + 0x7fffu + ((v.u >> 16) & 1u);
    return (unsigned short)(r >> 16);
}

// ---------------- Kernel 1: row L2-normalize, f32 -> bf16 --------------------
__global__ __launch_bounds__(256) void norm_rows_kernel(
    const float* __restrict__ z_i, const float* __restrict__ z_j,
    unsigned short* __restrict__ xn)
{
    const int row = blockIdx.x;
    const float* src = (row < HALF_N) ? (z_i + (size_t)row * DIMK)
                                      : (z_j + (size_t)(row - HALF_N) * DIMK);
    const int t = threadIdx.x;
    const float4 v = ((const float4*)src)[t];   // 256 threads * 4 = 1024 elems
    float ss = v.x * v.x + v.y * v.y + v.z * v.z + v.w * v.w;
    #pragma unroll
    for (int m = 1; m < 64; m <<= 1) ss += __shfl_xor(ss, m, 64);
    __shared__ float red[4];
    const int lane = t & 63, wave = t >> 6;
    if (lane == 0) red[wave] = ss;
    __syncthreads();
    ss = red[0] + red[1] + red[2] + red[3];
    const float rn = 1.0f / fmaxf(sqrtf(ss), 1e-8f);

    union { unsigned short s[4]; uint2 u; } pack;
    pack.s[0] = f32_to_bf16_rne(v.x * rn);
    pack.s[1] = f32_to_bf16_rne(v.y * rn);
    pack.s[2] = f32_to_bf16_rne(v.z * rn);
    pack.s[3] = f32_to_bf16_rne(v.w * rn);
    ((uint2*)(xn + (size_t)row * DIMK))[t] = pack.u;
}

// ---- Kernel 2: fused sim-GEMM (bf16 MFMA) + exp + per-row partial sums ------
// Upper-triangle blocks only (ip <= jp). 256 thr = 4 waves (2x2), each wave a
// 64x64 sub-tile = 4x4 frags of 16x16x32. LDS [128 rows][8 x 16B chunks],
// XOR-swizzled slot = r*8 + (c8 ^ (r&7)); staged via global_load_lds with the
// inverse swizzle applied to the per-lane GLOBAL source (rule 21 pattern).
__global__ __launch_bounds__(256) void simexp_kernel(
    const unsigned short* __restrict__ xn,
    float* __restrict__ partial,   // [NSLOTS][N_ROWS]
    float* __restrict__ tgt)       // [N_ROWS] target logit per row
{
    __shared__ u32x4 As[2][BM * (BK / 8)];   // 2 x 16 KiB
    __shared__ u32x4 Bs[2][BM * (BK / 8)];   // 2 x 16 KiB

    // decode (ip, jp) with ip <= jp from linear block id
    int rem = blockIdx.x;
    int ip = 0;
    while (rem >= NPANEL - ip) { rem -= NPANEL - ip; ++ip; }
    const int jp = ip + rem;

    const int t = threadIdx.x;
    const int lane = t & 63, wave = t >> 6;
    const int wm = wave >> 1, wn = wave & 1;
    const int rowBase = ip * BM, colBase = jp * BM;
    const int l15 = lane & 15, lhi = lane >> 4;

    f32x4 acc[4][4];
    #pragma unroll
    for (int i = 0; i < 4; ++i)
        #pragma unroll
        for (int j = 0; j < 4; ++j) {
            f32x4 z = {0.0f, 0.0f, 0.0f, 0.0f};
            acc[i][j] = z;
        }

    // ---- staging helper (macro to keep size arg a literal) ----
    // slot s = p*256 + wave*64 + lane (linear dest); source chunk inverse-swz.
#define STAGE(BUF, KT)                                                          \
    do {                                                                        \
        _Pragma("unroll")                                                       \
        for (int p = 0; p < 4; ++p) {                                           \
            const int segBase = p * 256 + wave * 64;                            \
            const int s  = segBase + lane;                                      \
            const int r  = s >> 3;                                              \
            const int c8 = (s & 7) ^ (r & 7);                                   \
            const unsigned short* gA =                                          \
                xn + (size_t)(rowBase + r) * DIMK + (KT) + c8 * 8;              \
            const unsigned short* gB =                                          \
                xn + (size_t)(colBase + r) * DIMK + (KT) + c8 * 8;              \
            __builtin_amdgcn_global_load_lds(                                   \
                (const __attribute__((address_space(1))) void*)gA,              \
                (__attribute__((address_space(3))) void*)&As[BUF][segBase],     \
                16, 0, 0);                                                      \
            __builtin_amdgcn_global_load_lds(                                   \
                (const __attribute__((address_space(1))) void*)gB,              \
                (__attribute__((address_space(3))) void*)&Bs[BUF][segBase],     \
                16, 0, 0);                                                      \
        }                                                                       \
    } while (0)

    // prologue
    STAGE(0, 0);
    asm volatile("s_waitcnt vmcnt(0)" ::: "memory");
    __syncthreads();

    int buf = 0;
    for (int ki = 0; ki < KSTEPS; ++ki) {
        if (ki + 1 < KSTEPS) STAGE(buf ^ 1, (ki + 1) * BK);

        // ---- compute from As/Bs[buf]: 2 x (8 ds_read_b128 + 16 MFMA)/wave ---
        #pragma unroll
        for (int kk = 0; kk < 2; ++kk) {
            const int kc = kk * 4 + lhi;   // k-chunk 0..7
            bf16x8 af[4], bfr[4];
            #pragma unroll
            for (int mi = 0; mi < 4; ++mi) {
                const int r = wm * 64 + mi * 16 + l15;
                af[mi] = __builtin_bit_cast(bf16x8, As[buf][r * 8 + (kc ^ (r & 7))]);
            }
            #pragma unroll
            for (int ni = 0; ni < 4; ++ni) {
                const int r = wn * 64 + ni * 16 + l15;
                bfr[ni] = __builtin_bit_cast(bf16x8, Bs[buf][r * 8 + (kc ^ (r & 7))]);
            }
            #pragma unroll
            for (int mi = 0; mi < 4; ++mi)
                #pragma unroll
                for (int ni = 0; ni < 4; ++ni)
                    acc[mi][ni] = __builtin_amdgcn_mfma_f32_16x16x32_bf16(
                        af[mi], bfr[ni], acc[mi][ni], 0, 0, 0);
        }

        // staged loads for buf^1 must land; reads of buf finished above.
        asm volatile("s_waitcnt vmcnt(0)" ::: "memory");
        __syncthreads();
        buf ^= 1;
    }
#undef STAGE

    // ---- epilogue ----
    // C/D layout (m89/m91): col = lane&15, row = (lane>>4)*4 + e
    const int colW = colBase + wn * 64;
    float cs[4] = {0.0f, 0.0f, 0.0f, 0.0f};   // column sums (transposed rows)
    #pragma unroll
    for (int mi = 0; mi < 4; ++mi) {
        const int rbase = rowBase + wm * 64 + mi * 16 + (lhi << 2);
        float rs[4] = {0.0f, 0.0f, 0.0f, 0.0f};
        #pragma unroll
        for (int ni = 0; ni < 4; ++ni) {
            const int gcol = colW + ni * 16 + l15;
            #pragma unroll
            for (int e = 0; e < 4; ++e) {
                const int grow = rbase + e;
                const float tv = acc[mi][ni][e] * 2.0f;     // /TEMPERATURE
                if (gcol == (grow ^ 1)) tgt[grow] = tv;     // diag blocks only
                const float ev = (gcol == grow) ? 0.0f : __expf(tv);
                rs[e] += ev;
                cs[ni] += ev;
            }
        }
        #pragma unroll
        for (int m = 1; m < 16; m <<= 1) {
            #pragma unroll
            for (int e = 0; e < 4; ++e) rs[e] += __shfl_xor(rs[e], m, 64);
        }
        if (l15 == 0) {
            float* dst = partial + (size_t)(jp * 2 + wn) * N_ROWS + rbase;
            dst[0] = rs[0]; dst[1] = rs[1]; dst[2] = rs[2]; dst[3] = rs[3];
        }
    }
    if (ip != jp) {
        // column sums -> rows of panel jp, summed over panel-ip cols (wm half)
        #pragma unroll
        for (int ni = 0; ni < 4; ++ni) {
            cs[ni] += __shfl_xor(cs[ni], 16, 64);
            cs[ni] += __shfl_xor(cs[ni], 32, 64);
        }
        if (lhi == 0) {
            float* dst = partial + (size_t)(ip * 2 + wm) * N_ROWS;
            #pragma unroll
            for (int ni = 0; ni < 4; ++ni)
                dst[colW + ni * 16 + l15] = cs[ni];
        }
    }
}

// ------------- Kernel 3: per-row LSE - target logit --------------------------
__global__ __launch_bounds__(256) void row_term_kernel(
    const float* __restrict__ partial, const float* __restrict__ tgt,
    float* __restrict__ terms)
{
    const int row = blockIdx.x * 256 + threadIdx.x;
    float s = 0.0f;
    for (int p = 0; p < NSLOTS; ++p) s += partial[(size_t)p * N_ROWS + row];
    terms[row] = logf(s) - tgt[row];
}

// ------------- Kernel 4: mean over rows --------------------------------------
__global__ __launch_bounds__(256) void loss_kernel(
    const float* __restrict__ terms, float* __restrict__ out)
{
    const int t = threadIdx.x;
    float s = 0.0f;
    for (int i = t; i < N_ROWS; i += 256) s += terms[i];
    #pragma unroll
    for (int m = 1; m < 64; m <<= 1) s += __shfl_xor(s, m, 64);
    __shared__ float red[4];
    if ((t & 63) == 0) red[t >> 6] = s;
    __syncthreads();
    if (t == 0) out[0] = (red[0] + red[1] + red[2] + red[3]) * (1.0f / N_ROWS);
}

extern "C" void kernel_launch(void* const* d_in, const int* in_sizes, int n_in,
                              void* d_out, int out_size, void* d_ws, size_t ws_size,
                              hipStream_t stream)
{
    const float* z_i = (const float*)d_in[0];
    const float* z_j = (const float*)d_in[1];
    float* out = (float*)d_out;

    // workspace layout
    unsigned short* xn = (unsigned short*)d_ws;                         // 16 MiB bf16
    float* partial = (float*)((char*)d_ws + (size_t)N_ROWS * DIMK * 2); // 4 MiB
    float* tgt     = partial + (size_t)NSLOTS * N_ROWS;                 // 32 KiB
    float* terms   = tgt + N_ROWS;                                      // 32 KiB

    const int ntri = NPANEL * (NPANEL + 1) / 2;   // 2080 blocks

    norm_rows_kernel<<<N_ROWS, 256, 0, stream>>>(z_i, z_j, xn);
    simexp_kernel<<<ntri, 256, 0, stream>>>(xn, partial, tgt);
    row_term_kernel<<<N_ROWS / 256, 256, 0, stream>>>(partial, tgt, terms);
    loss_kernel<<<1, 256, 0, stream>>>(terms, out);
}

// Round 3
// 137.331 us; speedup vs baseline: 1.4948x; 1.1599x over previous
//
#include <hip/hip_runtime.h>

// NT-Xent loss: z_i, z_j [4096,1024] f32 -> scalar f32 loss.
// loss = mean_i( log(sum_{j != i} exp(2*cos_sim(i,j))) - 2*cos_sim(i, i^1) )
//
// R3: 256x256-tile 8-phase schedule (T3+T4 counted vmcnt + T5 setprio),
//     triangle blocks (ip<=jp) with row+col exp-sum harvest,
//     global_load_lds w=16 with inverse-swizzled source (rule 21).

#define N_ROWS 8192
#define HALF_N 4096
#define DIMK   1024
#define BM     256
#define BK     64
#define NPANEL (N_ROWS / BM)   // 32
#define NSLOTS (NPANEL * 4)    // 128 partial slots per row
#define ITERS  (DIMK / (2 * BK))   // 8 (2 K-tiles per iteration)

typedef float        f32x4  __attribute__((ext_vector_type(4)));
typedef unsigned int u32x4  __attribute__((ext_vector_type(4)));
typedef __bf16       bf16x8 __attribute__((ext_vector_type(8)));

__device__ __forceinline__ unsigned short f32_to_bf16_rne(float f) {
    union { float f; unsigned int u; } v; v.f = f;
    unsigned int r = v.u + 0x7fffu + ((v.u >> 16) & 1u);
    return (unsigned short)(r >> 16);
}

// ---------------- Kernel 1: row L2-normalize, f32 -> bf16 --------------------
__global__ __launch_bounds__(256) void norm_rows_kernel(
    const float* __restrict__ z_i, const float* __restrict__ z_j,
    unsigned short* __restrict__ xn)
{
    const int row = blockIdx.x;
    const float* src = (row < HALF_N) ? (z_i + (size_t)row * DIMK)
                                      : (z_j + (size_t)(row - HALF_N) * DIMK);
    const int t = threadIdx.x;
    const float4 v = ((const float4*)src)[t];
    float ss = v.x * v.x + v.y * v.y + v.z * v.z + v.w * v.w;
    #pragma unroll
    for (int m = 1; m < 64; m <<= 1) ss += __shfl_xor(ss, m, 64);
    __shared__ float red[4];
    const int lane = t & 63, wave = t >> 6;
    if (lane == 0) red[wave] = ss;
    __syncthreads();
    ss = red[0] + red[1] + red[2] + red[3];
    const float rn = 1.0f / fmaxf(sqrtf(ss), 1e-8f);

    union { unsigned short s[4]; uint2 u; } pack;
    pack.s[0] = f32_to_bf16_rne(v.x * rn);
    pack.s[1] = f32_to_bf16_rne(v.y * rn);
    pack.s[2] = f32_to_bf16_rne(v.z * rn);
    pack.s[3] = f32_to_bf16_rne(v.w * rn);
    ((uint2*)(xn + (size_t)row * DIMK))[t] = pack.u;
}

// ---- Kernel 2: fused sim-GEMM (bf16 MFMA, 256^2 8-phase) + exp row sums -----
__device__ __forceinline__ bf16x8 ldfrag(const u32x4* buf, int r, int kc) {
    return __builtin_bit_cast(bf16x8, buf[r * 8 + (kc ^ (r & 7))]);
}

#define BAR() do { asm volatile("" ::: "memory"); \
                   __builtin_amdgcn_s_barrier();  \
                   asm volatile("" ::: "memory"); } while (0)
#define WAITVM(N) asm volatile("s_waitcnt vmcnt(" #N ")" ::: "memory")
#define GLDS(gp, lp) __builtin_amdgcn_global_load_lds(                          \
        (const __attribute__((address_space(1))) void*)(gp),                    \
        (__attribute__((address_space(3))) void*)(lp), 16, 0, 0)

__global__ __launch_bounds__(512, 2) void simexp_kernel(
    const unsigned short* __restrict__ xn,
    float* __restrict__ partial,   // [NSLOTS][N_ROWS]
    float* __restrict__ tgt)       // [N_ROWS]
{
    __shared__ u32x4 As[2][BM * 8];   // 2 x 32 KiB  (256 rows x 8 chunks of 16B)
    __shared__ u32x4 Bs[2][BM * 8];   // 2 x 32 KiB

    // bijective XCD swizzle (m204): nwg=528, q=66, r=0
    const int orig = blockIdx.x;
    const int bid  = (orig & 7) * 66 + (orig >> 3);

    // decode (ip, jp) with ip <= jp
    int rem = bid, ip = 0;
    while (rem >= NPANEL - ip) { rem -= NPANEL - ip; ++ip; }
    const int jp = ip + rem;

    const int t = threadIdx.x;
    const int lane = t & 63, wave = t >> 6;
    const int wm = wave >> 2, wn = wave & 3;   // 2 x 4 wave grid
    const int rowBase = ip * BM, colBase = jp * BM;
    const int l15 = lane & 15, lhi = lane >> 4;

    // staging geometry: per STAGEU (one 128-row half-tile), thread does 2 loads
    const int r_lo = t >> 3;                         // 0..63
    const int c8e  = (((t & 7) ^ (r_lo & 7)) << 3);  // inverse-swizzled k-chunk elem off

    // STAGEU(BUF, SLOT, HALF, PANROW, KTILE): stage rows [HALF*128, +128) of
    // panel PANROW, k-window KTILE, into BUF[SLOT] half region (linear dest).
#define STAGEU(BUF, SLOT, HALF, PANROW, KTILE) do {                              \
        const unsigned short* _g0 = xn +                                         \
            (size_t)((PANROW) + (HALF) * 128 + r_lo) * DIMK + (KTILE) * BK + c8e;\
        const unsigned short* _g1 = xn +                                         \
            (size_t)((PANROW) + (HALF) * 128 + 64 + r_lo) * DIMK + (KTILE) * BK + c8e;\
        GLDS(_g0, &BUF[SLOT][(HALF) * 1024 + wave * 64]);                        \
        GLDS(_g1, &BUF[SLOT][(HALF) * 1024 + 512 + wave * 64]);                  \
    } while (0)

    f32x4 acc[8][4];
    #pragma unroll
    for (int i = 0; i < 8; ++i)
        #pragma unroll
        for (int j = 0; j < 4; ++j) {
            f32x4 z = {0.0f, 0.0f, 0.0f, 0.0f};
            acc[i][j] = z;
        }

    bf16x8 bfr[4][2];   // B frags for current K-tile (all ni, both kk)
    bf16x8 af[2][2];    // A frags for current quadrant

#define LOAD_B(BP) do { _Pragma("unroll")                                        \
        for (int ni = 0; ni < 4; ++ni) {                                         \
            const int r = wn * 64 + ni * 16 + l15;                               \
            bfr[ni][0] = ldfrag(BP, r, lhi);                                     \
            bfr[ni][1] = ldfrag(BP, r, 4 + lhi);                                 \
        } } while (0)
#define LOAD_A(AP, Q) do { _Pragma("unroll")                                     \
        for (int m2 = 0; m2 < 2; ++m2) {                                         \
            const int r = wm * 128 + ((Q) * 2 + m2) * 16 + l15;                  \
            af[m2][0] = ldfrag(AP, r, lhi);                                      \
            af[m2][1] = ldfrag(AP, r, 4 + lhi);                                  \
        } } while (0)
#define MFMA16(Q) do {                                                           \
        __builtin_amdgcn_s_setprio(1);                                           \
        _Pragma("unroll")                                                        \
        for (int m2 = 0; m2 < 2; ++m2)                                           \
            _Pragma("unroll")                                                    \
            for (int ni = 0; ni < 4; ++ni)                                       \
                _Pragma("unroll")                                                \
                for (int kk = 0; kk < 2; ++kk)                                   \
                    acc[(Q) * 2 + m2][ni] = __builtin_amdgcn_mfma_f32_16x16x32_bf16( \
                        af[m2][kk], bfr[ni][kk], acc[(Q) * 2 + m2][ni], 0, 0, 0);\
        __builtin_amdgcn_s_setprio(0);                                           \
    } while (0)

    const u32x4* A0p = &As[0][0]; const u32x4* B0p = &Bs[0][0];
    const u32x4* A1p = &As[1][0]; const u32x4* B1p = &Bs[1][0];

    // ---- prologue: ktile0 (A+B, slot0) + ktile1 B (slot1); keep newest 4 ----
    STAGEU(As, 0, 0, rowBase, 0); STAGEU(As, 0, 1, rowBase, 0);
    STAGEU(Bs, 0, 0, colBase, 0); STAGEU(Bs, 0, 1, colBase, 0);
    STAGEU(Bs, 1, 0, colBase, 1); STAGEU(Bs, 1, 1, colBase, 1);
    WAITVM(4);          // drain ktile0 (8 instrs); ktile1-B (4) stays in flight
    BAR();

    for (int it = 0; it < ITERS; ++it) {
        const int kA = 2 * it;
        const bool nx = (it + 1 < ITERS);
        // ================= phases 1-4: K-tile kA (slot 0) =================
        // ph1: B frags + A q0; stage slot1-A (ktile kA+1; old reads done ph8 prev)
        LOAD_B(B0p); LOAD_A(A0p, 0);
        STAGEU(As, 1, 0, rowBase, kA + 1); STAGEU(As, 1, 1, rowBase, kA + 1);
        BAR(); MFMA16(0); BAR();
        // ph2: A q1; stage slot0-B half0 (ktile kA+2; slot0-B reads done ph1)
        LOAD_A(A0p, 1); if (nx) STAGEU(Bs, 0, 0, colBase, kA + 2);
        BAR(); MFMA16(1); BAR();
        // ph3: A q2; stage slot0-B half1
        LOAD_A(A0p, 2); if (nx) STAGEU(Bs, 0, 1, colBase, kA + 2);
        BAR(); MFMA16(2); BAR();
        // ph4: A q3; vmcnt(4) keeps only ph2+ph3 stages -> slot1 fully landed
        LOAD_A(A0p, 3);
        BAR(); MFMA16(3);
        if (nx) { WAITVM(4); } else { WAITVM(0); }
        BAR();
        // ================= phases 5-8: K-tile kA+1 (slot 1) ===============
        // ph5: B frags + A q0; stage slot0-A (ktile kA+2; slot0-A reads done ph4)
        LOAD_B(B1p); LOAD_A(A1p, 0);
        if (nx) { STAGEU(As, 0, 0, rowBase, kA + 2); STAGEU(As, 0, 1, rowBase, kA + 2); }
        BAR(); MFMA16(0); BAR();
        // ph6: A q1; stage slot1-B half0 (ktile kA+3; slot1-B reads done ph5)
        LOAD_A(A1p, 1); if (nx) STAGEU(Bs, 1, 0, colBase, kA + 3);
        BAR(); MFMA16(1); BAR();
        // ph7: A q2; stage slot1-B half1
        LOAD_A(A1p, 2); if (nx) STAGEU(Bs, 1, 1, colBase, kA + 3);
        BAR(); MFMA16(2); BAR();
        // ph8: A q3; vmcnt(4) keeps only ph6+ph7 stages -> slot0 fully landed
        LOAD_A(A1p, 3);
        BAR(); MFMA16(3);
        if (nx) { WAITVM(4); }
        BAR();
    }
#undef STAGEU
#undef LOAD_A
#undef LOAD_B
#undef MFMA16

    // ---- epilogue: logits, diag mask, target capture, per-row exp sums ----
    // C/D layout (m89/m91): col = lane&15, row = (lane>>4)*4 + e
    const int colW = colBase + wn * 64;
    float cs[4] = {0.0f, 0.0f, 0.0f, 0.0f};
    #pragma unroll
    for (int mi = 0; mi < 8; ++mi) {
        const int rbase = rowBase + wm * 128 + mi * 16 + (lhi << 2);
        float rs[4] = {0.0f, 0.0f, 0.0f, 0.0f};
        #pragma unroll
        for (int ni = 0; ni < 4; ++ni) {
            const int gcol = colW + ni * 16 + l15;
            #pragma unroll
            for (int e = 0; e < 4; ++e) {
                const int grow = rbase + e;
                const float tv = acc[mi][ni][e] * 2.0f;     // /TEMPERATURE
                if (gcol == (grow ^ 1)) tgt[grow] = tv;     // diag blocks only
                const float ev = (gcol == grow) ? 0.0f : __expf(tv);
                rs[e] += ev;
                cs[ni] += ev;
            }
        }
        #pragma unroll
        for (int m = 1; m < 16; m <<= 1) {
            #pragma unroll
            for (int e = 0; e < 4; ++e) rs[e] += __shfl_xor(rs[e], m, 64);
        }
        if (l15 == 0) {
            float* dst = partial + (size_t)(jp * 4 + wn) * N_ROWS + rbase;
            dst[0] = rs[0]; dst[1] = rs[1]; dst[2] = rs[2]; dst[3] = rs[3];
        }
    }
    if (ip != jp) {
        // column sums -> rows of panel jp, summed over this block's wm-half rows
        #pragma unroll
        for (int ni = 0; ni < 4; ++ni) {
            cs[ni] += __shfl_xor(cs[ni], 16, 64);
            cs[ni] += __shfl_xor(cs[ni], 32, 64);
        }
        if (lhi == 0) {
            float* dst = partial + (size_t)(ip * 4 + wm) * N_ROWS;
            #pragma unroll
            for (int ni = 0; ni < 4; ++ni)
                dst[colW + ni * 16 + l15] = cs[ni];
        }
    }
}

// ------------- Kernel 3: per-row LSE - target logit --------------------------
// Valid slots for row in panel P: {pan*4+s, s<4 : pan>=P} U {pan*4+s, s<2 : pan<P}
__global__ __launch_bounds__(256) void row_term_kernel(
    const float* __restrict__ partial, const float* __restrict__ tgt,
    float* __restrict__ terms)
{
    const int row = blockIdx.x * 256 + threadIdx.x;
    const int P = row >> 8;
    float s = 0.0f;
    for (int pan = 0; pan < NPANEL; ++pan) {
        const float* base = partial + (size_t)pan * 4 * N_ROWS + row;
        s += base[0] + base[(size_t)N_ROWS];
        if (pan >= P) s += base[(size_t)2 * N_ROWS] + base[(size_t)3 * N_ROWS];
    }
    terms[row] = logf(s) - tgt[row];
}

// ------------- Kernel 4: mean over rows --------------------------------------
__global__ __launch_bounds__(256) void loss_kernel(
    const float* __restrict__ terms, float* __restrict__ out)
{
    const int t = threadIdx.x;
    float s = 0.0f;
    for (int i = t; i < N_ROWS; i += 256) s += terms[i];
    #pragma unroll
    for (int m = 1; m < 64; m <<= 1) s += __shfl_xor(s, m, 64);
    __shared__ float red[4];
    if ((t & 63) == 0) red[t >> 6] = s;
    __syncthreads();
    if (t == 0) out[0] = (red[0] + red[1] + red[2] + red[3]) * (1.0f / N_ROWS);
}

extern "C" void kernel_launch(void* const* d_in, const int* in_sizes, int n_in,
                              void* d_out, int out_size, void* d_ws, size_t ws_size,
                              hipStream_t stream)
{
    const float* z_i = (const float*)d_in[0];
    const float* z_j = (const float*)d_in[1];
    float* out = (float*)d_out;

    unsigned short* xn = (unsigned short*)d_ws;                         // 16 MiB bf16
    float* partial = (float*)((char*)d_ws + (size_t)N_ROWS * DIMK * 2); // 4 MiB
    float* tgt     = partial + (size_t)NSLOTS * N_ROWS;                 // 32 KiB
    float* terms   = tgt + N_ROWS;                                      // 32 KiB

    const int ntri = NPANEL * (NPANEL + 1) / 2;   // 528 blocks

    norm_rows_kernel<<<N_ROWS, 256, 0, stream>>>(z_i, z_j, xn);
    simexp_kernel<<<ntri, 512, 0, stream>>>(xn, partial, tgt);
    row_term_kernel<<<N_ROWS / 256, 256, 0, stream>>>(partial, tgt, terms);
    loss_kernel<<<1, 256, 0, stream>>>(terms, out);
}